// Round 6
// baseline (598.710 us; speedup 1.0000x reference)
//
#include <hip/hip_runtime.h>
#include <hip/hip_bf16.h>
#include <math.h>

#define EPS 1e-5f

static constexpr int N_ = 128, C_ = 128, T_ = 256, V_ = 21, E_ = 8, M_ = 13;
static constexpr int TV_ = T_ * V_;   // 5376
static constexpr int NT_ = 4;         // t's per sub-tile
static constexpr int ST_ = NT_ * V_;  // 84 s-columns per sub-tile
static constexpr int NSUB = 4;        // sub-tiles per block
static constexpr int BT_ = NT_ * NSUB;        // 16 t's per block
static constexpr int SBUF = 96 * 256;         // 24576 B per staging buffer
static constexpr int XF_PITCH = 48;           // bytes per xf row (24 bf16, 21 used)

// staging swizzle: spreads writers over (s&7) and (s>>3)
#define SWZ(s)  (((((s) & 7) ^ ((((s) >> 3) & 3) << 1))) << 4)
// xf row xor (bijective within 32-row groups; identical on read & write)
#define EXOR(r) ((((r) >> 5) & 3) << 4)

typedef short bf16x8 __attribute__((ext_vector_type(8)));
typedef short s16x4  __attribute__((ext_vector_type(4)));
typedef float f32x4  __attribute__((ext_vector_type(4)));

__device__ inline short f2bf(float v) {
    __hip_bfloat16 b = __float2bfloat16(v);
    return *reinterpret_cast<short*>(&b);
}

// ---------------- Kernel P: fold BN + convert W to bf16 ----------------
__global__ __launch_bounds__(256) void prep_kernel(
    const float* __restrict__ ft_w, const float* __restrict__ ft_b,
    const float* __restrict__ ft_gamma, const float* __restrict__ ft_beta,
    const float* __restrict__ ft_mean, const float* __restrict__ ft_var,
    __hip_bfloat16* __restrict__ w_bf, float* __restrict__ sc_g, float* __restrict__ sh_g)
{
    int tid = blockIdx.x * 256 + threadIdx.x;
    if (tid < C_ * C_) w_bf[tid] = __float2bfloat16(ft_w[tid]);
    if (tid < C_) {
        float sc = ft_gamma[tid] * rsqrtf(ft_var[tid] + EPS);
        sc_g[tid] = sc;
        sh_g[tid] = (ft_b[tid] - ft_mean[tid]) * sc + ft_beta[tid];
    }
}

// ---------------- Kernel A: mean over T ----------------
__global__ __launch_bounds__(256) void mean_kernel(const float* __restrict__ x,
                                                   float* __restrict__ xm) {
    __shared__ float slab[TV_];
    __shared__ float partial[V_ * 8];
    const int nc = blockIdx.x;
    const int tid = threadIdx.x;
    const float4* src4 = (const float4*)(x + (size_t)nc * TV_);
    float4* slab4 = (float4*)slab;
    #pragma unroll
    for (int it = 0; it < 6; ++it) {
        int idx = it * 256 + tid;
        if (idx < TV_ / 4) slab4[idx] = src4[idx];
    }
    __syncthreads();
    if (tid < V_ * 8) {
        int v = tid >> 3, g = tid & 7;
        float s = 0.f;
        #pragma unroll
        for (int tt = 0; tt < 32; ++tt) s += slab[(g * 32 + tt) * V_ + v];
        partial[v * 8 + g] = s;
    }
    __syncthreads();
    if (tid < V_) {
        float s = 0.f;
        #pragma unroll
        for (int g = 0; g < 8; ++g) s += partial[tid * 8 + g];
        xm[(size_t)nc * V_ + tid] = s * (1.0f / T_);
    }
}

// ---------------- Kernel B: H_dyn + A = H^T H (bf16, 32x32 zero-padded) ----------------
__global__ __launch_bounds__(64) void hyper_kernel(
    const float* __restrict__ xm, const float* __restrict__ dyn_w,
    const float* __restrict__ dyn_b,
    const float* __restrict__ dyn_gamma, const float* __restrict__ dyn_beta,
    const float* __restrict__ dyn_mean, const float* __restrict__ dyn_var,
    __hip_bfloat16* __restrict__ A_bf)               // (N,32,32)
{
    __shared__ float xs[C_ * V_];
    __shared__ float Hs[M_ * V_];
    const int n = blockIdx.x;
    const int l = threadIdx.x;
    const float* src = xm + (size_t)n * C_ * V_;
    for (int idx = l; idx < C_ * V_; idx += 64) xs[idx] = src[idx];
    __syncthreads();
    for (int idx = l; idx < E_ * V_; idx += 64) {
        int e = idx / V_, v = idx - e * V_;
        float acc = 0.f;
        for (int c = 0; c < C_; ++c) acc = fmaf(xs[c * V_ + v], dyn_w[e * C_ + c], acc);
        acc += dyn_b[e];
        float scale = dyn_gamma[e] * rsqrtf(dyn_var[e] + EPS);
        acc = (acc - dyn_mean[e]) * scale + dyn_beta[e];
        Hs[idx] = fmaxf(acc, 0.f);
    }
    __syncthreads();
    if (l < E_) {
        float row[V_];
        float mx = -1e30f;
        #pragma unroll
        for (int v = 0; v < V_; ++v) { row[v] = Hs[l * V_ + v]; mx = fmaxf(mx, row[v]); }
        float s = 0.f;
        #pragma unroll
        for (int v = 0; v < V_; ++v) { row[v] = __expf(row[v] - mx); s += row[v]; }
        float inv = 1.0f / s;
        #pragma unroll
        for (int v = 0; v < V_; ++v) Hs[l * V_ + v] = row[v] * inv;
    } else if (l < M_) {
        int i = l - E_;
        #pragma unroll
        for (int v = 0; v < V_; ++v)
            Hs[l * V_ + v] = (v >= 1 + 4 * i && v < 5 + 4 * i) ? 1.0f : 0.0f;
    }
    __syncthreads();
    for (int idx = l; idx < 32 * 32; idx += 64) {
        int u = idx >> 5, v = idx & 31;
        float s = 0.f;
        if (u < V_ && v < V_) {
            #pragma unroll
            for (int m = 0; m < M_; ++m) s = fmaf(Hs[m * V_ + u], Hs[m * V_ + v], s);
        }
        A_bf[(size_t)n * 1024 + idx] = __float2bfloat16(s);
    }
}

// ---------------- Kernel C: pipelined MFMA GEMM + BN/ReLU + MFMA A-transform + residual ----------------
// grid (16 t-groups, 128 n), 512 threads = 8 waves. Block covers 16 t's as 4 pipelined sub-tiles.
__global__ __launch_bounds__(512, 4) void main_kernel(
    const float* __restrict__ x, const __hip_bfloat16* __restrict__ w_bf,
    const float* __restrict__ sc_g, const float* __restrict__ sh_g,
    const __hip_bfloat16* __restrict__ A_bf, float* __restrict__ out)
{
    // two staging buffers [s=96][c=128] bf16; xf (512 rows x 48 B) overlays the
    // buffer whose staging data was just consumed. 64 B finite tail for the
    // row-511 k-pad overspill read.
    __shared__ __align__(16) char lds[2 * SBUF + 64];
    __shared__ float sc_s[C_], sh_s[C_];

    const int gt = blockIdx.x;    // 0..15
    const int n  = blockIdx.y;    // 0..127
    const int tid = threadIdx.x;
    const int w = tid >> 6;       // wave 0..7
    const int l = tid & 63;
    const int hi = l >> 4;        // 0..3
    const int lo = l & 15;
    const int t0 = gt * BT_;
    const size_t xn = (size_t)n * C_ * TV_;

    if (tid < C_) { sc_s[tid] = sc_g[tid]; sh_s[tid] = sh_g[tid]; }
    if (tid < 16) *(int*)(lds + 2 * SBUF + tid * 4) = 0;

    // GEMM1 A-operand (W) fragments, loaded once
    const int o_row = 16 * w + lo;
    bf16x8 wf[4];
    #pragma unroll
    for (int kk = 0; kk < 4; ++kk)
        wf[kk] = *(const bf16x8*)((const short*)w_bf + o_row * C_ + kk * 32 + 8 * hi);

    // GEMM2 B-operand (A, symmetric) fragments, loaded once
    const short* Abf_n = (const short*)A_bf + (size_t)n * 1024;
    const bf16x8 bA0 = *(const bf16x8*)(Abf_n + lo * 32 + 8 * hi);         // v = 0..15
    const bf16x8 bA1 = *(const bf16x8*)(Abf_n + (16 + lo) * 32 + 8 * hi);  // v = 16..31

    // staging work items: 672 = 32 cg x 21 q; item -> 4 c's x 4 s's (16B loads)
    const int cg0 = tid / 21,          q0 = tid - cg0 * 21;
    const int cg1 = (tid + 512) / 21,  q1 = (tid + 512) - cg1 * 21;
    const int c00 = cg0 * 4, sq0 = q0 * 4;
    const int c01 = cg1 * 4, sq1 = q1 * 4;
    const bool has2 = (tid < 672 - 512);

    f32x4 pf[8];

    auto issue_loads = [&](int it) {
        const float* src = x + xn + (size_t)(t0 + it * NT_) * V_;
        #pragma unroll
        for (int i = 0; i < 4; ++i)
            pf[i] = *(const f32x4*)(src + (size_t)(c00 + i) * TV_ + sq0);
        if (has2) {
            #pragma unroll
            for (int i = 0; i < 4; ++i)
                pf[4 + i] = *(const f32x4*)(src + (size_t)(c01 + i) * TV_ + sq1);
        }
    };
    auto write_stage = [&](char* buf) {
        #pragma unroll
        for (int i = 0; i < 4; ++i) {
            int s = sq0 + i;
            s16x4 pk = { f2bf(pf[0][i]), f2bf(pf[1][i]), f2bf(pf[2][i]), f2bf(pf[3][i]) };
            *(s16x4*)(buf + ((s * 256 + c00 * 2) ^ SWZ(s))) = pk;
        }
        if (has2) {
            #pragma unroll
            for (int i = 0; i < 4; ++i) {
                int s = sq1 + i;
                s16x4 pk = { f2bf(pf[4][i]), f2bf(pf[5][i]), f2bf(pf[6][i]), f2bf(pf[7][i]) };
                *(s16x4*)(buf + ((s * 256 + c01 * 2) ^ SWZ(s))) = pk;
            }
        }
        // keep pad rows (s=84..95) finite-zero: xf overlays corrupt them each round
        if (tid < 384) {
            int srow = ST_ + (tid >> 5);
            int k8 = (tid & 31) * 8;
            *(unsigned long long*)(buf + ((srow * 256 + k8) ^ SWZ(srow))) = 0ull;
        }
    };

    // prologue: stage sub-tile 0 into buffer 0
    issue_loads(0);
    write_stage(lds);
    __syncthreads();

    const int obase = 16 * w + 4 * hi;
    float scr[4], shr[4];
    #pragma unroll
    for (int r = 0; r < 4; ++r) { scr[r] = sc_s[obase + r]; shr[r] = sh_s[obase + r]; }

    #pragma unroll
    for (int it = 0; it < NSUB; ++it) {
        char* Scur = lds + (it & 1) * SBUF;
        char* Snxt = lds + ((it & 1) ^ 1) * SBUF;

        if (it < NSUB - 1) issue_loads(it + 1);   // in flight across all compute below

        // GEMM1: 6 N-frags, K=128 in 4 steps
        f32x4 acc[6];
        #pragma unroll
        for (int nf = 0; nf < 6; ++nf) acc[nf] = (f32x4){0.f, 0.f, 0.f, 0.f};
        #pragma unroll
        for (int kk = 0; kk < 4; ++kk) {
            #pragma unroll
            for (int nf = 0; nf < 6; ++nf) {
                int srow = 16 * nf + lo;
                int byte = (srow * 256 + (kk * 32 + 8 * hi) * 2) ^ SWZ(srow);
                bf16x8 b = *(const bf16x8*)(Scur + byte);
                acc[nf] = __builtin_amdgcn_mfma_f32_16x16x32_bf16(wf[kk], b, acc[nf], 0, 0, 0);
            }
        }
        __syncthreads();   // B1: GEMM1 reads (and prev GEMM2 reads) done

        // BN + ReLU -> xf bf16 into Scur (overlay)
        #pragma unroll
        for (int nf = 0; nf < 6; ++nf) {
            int s = 16 * nf + lo;
            if (s < ST_) {
                int t = s / V_, u = s - t * V_;
                #pragma unroll
                for (int r = 0; r < 4; ++r) {
                    float vv = fmaxf(fmaf(acc[nf][r], scr[r], shr[r]), 0.f);
                    int row = (obase + r) * NT_ + t;
                    *(short*)(Scur + ((row * XF_PITCH + u * 2) ^ EXOR(row))) = f2bf(vv);
                }
            }
        }
        if (it < NSUB - 1) write_stage(Snxt);     // stage next sub-tile
        __syncthreads();   // B2: xf + stage writes visible

        // GEMM2: Xr = xf (512x32) * A (32x32); wave w owns M-frags 4w..4w+3
        bf16x8 xfr[4];
        #pragma unroll
        for (int i = 0; i < 4; ++i) {
            int row = 16 * (4 * w + i) + lo;
            xfr[i] = *(const bf16x8*)(Scur + ((row * XF_PITCH + 16 * hi) ^ EXOR(row)));
        }
        #pragma unroll
        for (int i = 0; i < 4; ++i) {
            f32x4 d0 = (f32x4){0.f, 0.f, 0.f, 0.f};
            f32x4 d1 = (f32x4){0.f, 0.f, 0.f, 0.f};
            d0 = __builtin_amdgcn_mfma_f32_16x16x32_bf16(xfr[i], bA0, d0, 0, 0, 0);
            d1 = __builtin_amdgcn_mfma_f32_16x16x32_bf16(xfr[i], bA1, d1, 0, 0, 0);
            int row0 = 16 * (4 * w + i) + 4 * hi;
            #pragma unroll
            for (int r = 0; r < 4; ++r) {
                int row = row0 + r;
                int o = row >> 2, tl = row & 3;
                size_t g = xn + (size_t)o * TV_ + (size_t)(t0 + it * NT_ + tl) * V_;
                out[g + lo] = d0[r] + x[g + lo];
                if (lo < V_ - 16) out[g + 16 + lo] = d1[r] + x[g + 16 + lo];
            }
        }
    }
}

extern "C" void kernel_launch(void* const* d_in, const int* in_sizes, int n_in,
                              void* d_out, int out_size, void* d_ws, size_t ws_size,
                              hipStream_t stream) {
    const float* x         = (const float*)d_in[0];
    const float* dyn_w     = (const float*)d_in[1];
    const float* dyn_b     = (const float*)d_in[2];
    const float* dyn_gamma = (const float*)d_in[3];
    const float* dyn_beta  = (const float*)d_in[4];
    const float* dyn_mean  = (const float*)d_in[5];
    const float* dyn_var   = (const float*)d_in[6];
    const float* ft_w      = (const float*)d_in[7];
    const float* ft_b      = (const float*)d_in[8];
    const float* ft_gamma  = (const float*)d_in[9];
    const float* ft_beta   = (const float*)d_in[10];
    const float* ft_mean   = (const float*)d_in[11];
    const float* ft_var    = (const float*)d_in[12];
    float* out = (float*)d_out;

    char* ws = (char*)d_ws;
    float* xm  = (float*)ws;                                   ws += (size_t)N_ * C_ * V_ * 4;
    __hip_bfloat16* A_bf = (__hip_bfloat16*)ws;                ws += (size_t)N_ * 1024 * 2;
    __hip_bfloat16* w_bf = (__hip_bfloat16*)ws;                ws += (size_t)C_ * C_ * 2;
    float* sc_g = (float*)ws;                                  ws += C_ * 4;
    float* sh_g = (float*)ws;                                  ws += C_ * 4;

    prep_kernel<<<64, 256, 0, stream>>>(ft_w, ft_b, ft_gamma, ft_beta, ft_mean, ft_var,
                                        w_bf, sc_g, sh_g);
    mean_kernel<<<N_ * C_, 256, 0, stream>>>(x, xm);
    hyper_kernel<<<N_, 64, 0, stream>>>(xm, dyn_w, dyn_b, dyn_gamma, dyn_beta,
                                        dyn_mean, dyn_var, A_bf);
    main_kernel<<<dim3(T_ / BT_, N_), 512, 0, stream>>>(x, w_bf, sc_g, sh_g, A_bf, out);
}